// Round 1
// baseline (455.090 us; speedup 1.0000x reference)
//
#include <hip/hip_runtime.h>

#define CIN 64
#define COUT 32

// Kernel 1: out[r, c] = bias[c] for all rows. Vectorized float4 stores.
__global__ __launch_bounds__(256) void bias_init_kernel(
    float* __restrict__ out, const float* __restrict__ bias, int total)
{
    int i = (blockIdx.x * blockDim.x + threadIdx.x) * 4;
    if (i < total) {
        int ch = i & (COUT - 1);           // COUT=32, i is 4-aligned
        float4 b;
        b.x = bias[ch + 0];
        b.y = bias[ch + 1];
        b.z = bias[ch + 2];
        b.w = bias[ch + 3];
        *reinterpret_cast<float4*>(out + i) = b;
    }
}

// Kernel 2: one 32-lane group per pair. lane = output channel.
// blockIdx.y = k (kernel offset), so the weight column W[k][:,lane]
// is block-uniform and lives in 64 VGPRs for the whole block.
__global__ __launch_bounds__(256) void scatter_gemm_kernel(
    const float* __restrict__ feats,
    const float* __restrict__ weight,
    const int* __restrict__ in_idx,
    const int* __restrict__ out_idx,
    float* __restrict__ out,
    int P, int n_groups)
{
    const int k       = blockIdx.y;
    const int lane    = threadIdx.x & 31;
    const int group_id = blockIdx.x * (blockDim.x >> 5) + (threadIdx.x >> 5);

    // Hoist weight column into registers: coalesced loads (lane-contiguous).
    float w[CIN];
    const float* __restrict__ Wk = weight + (long)k * CIN * COUT;
    #pragma unroll
    for (int c = 0; c < CIN; ++c) w[c] = Wk[c * COUT + lane];

    const int base = k * P;
    for (int p = group_id; p < P; p += n_groups) {
        const int in = in_idx[base + p];
        const int o  = out_idx[base + p];
        const float4* __restrict__ fr =
            reinterpret_cast<const float4*>(feats + (long)in * CIN);
        float acc = 0.0f;
        #pragma unroll
        for (int c4 = 0; c4 < CIN / 4; ++c4) {
            float4 f = fr[c4];             // group-uniform broadcast load
            acc += f.x * w[4 * c4 + 0];
            acc += f.y * w[4 * c4 + 1];
            acc += f.z * w[4 * c4 + 2];
            acc += f.w * w[4 * c4 + 3];
        }
        atomicAdd(out + (long)o * COUT + lane, acc);
    }
}

extern "C" void kernel_launch(void* const* d_in, const int* in_sizes, int n_in,
                              void* d_out, int out_size, void* d_ws, size_t ws_size,
                              hipStream_t stream) {
    const float* feats   = (const float*)d_in[0];
    const float* weight  = (const float*)d_in[1];
    const float* bias    = (const float*)d_in[2];
    const int*   in_idx  = (const int*)d_in[3];
    const int*   out_idx = (const int*)d_in[4];
    float*       out     = (float*)d_out;

    const int K = in_sizes[1] / (CIN * COUT);   // 27
    const int P = in_sizes[3] / K;              // 50000

    // 1) out = bias (broadcast)
    int total4 = out_size / 4;
    bias_init_kernel<<<(total4 + 255) / 256, 256, 0, stream>>>(out, bias, out_size);

    // 2) gather -> GEMV -> scatter-add
    const int blocks_x = 96;                    // 96*8 = 768 groups per k
    const int n_groups = blocks_x * (256 / 32);
    dim3 grid(blocks_x, K);
    scatter_gemm_kernel<<<grid, 256, 0, stream>>>(feats, weight, in_idx, out_idx,
                                                  out, P, n_groups);
}

// Round 2
// 433.203 us; speedup vs baseline: 1.0505x; 1.0505x over previous
//
#include <hip/hip_runtime.h>

#define CIN 64
#define COUT 32

// Kernel 1: out[r, c] = bias[c] for all rows. Vectorized float4 stores.
__global__ __launch_bounds__(256) void bias_init_kernel(
    float* __restrict__ out, const float* __restrict__ bias, int total)
{
    int i = (blockIdx.x * blockDim.x + threadIdx.x) * 4;
    if (i < total) {
        int ch = i & (COUT - 1);           // COUT=32, i is 4-aligned
        float4 b;
        b.x = bias[ch + 0];
        b.y = bias[ch + 1];
        b.z = bias[ch + 2];
        b.w = bias[ch + 3];
        *reinterpret_cast<float4*>(out + i) = b;
    }
}

// Kernel 2: one 32-lane group per chunk of 32 pairs. lane = output channel.
// Index loads are coalesced (1 dword per lane per chunk) and broadcast via
// __shfl; the pair loop is unrolled so multiple feats-row load streams are
// in flight simultaneously.
__global__ __launch_bounds__(256) void scatter_gemm_kernel(
    const float* __restrict__ feats,
    const float* __restrict__ weight,
    const int* __restrict__ in_idx,
    const int* __restrict__ out_idx,
    float* __restrict__ out,
    int P, int n_groups)
{
    const int k        = blockIdx.y;
    const int lane     = threadIdx.x & 31;
    const int group_id = blockIdx.x * (blockDim.x >> 5) + (threadIdx.x >> 5);

    // Hoist weight column into registers: coalesced loads (lane-contiguous).
    float w[CIN];
    const float* __restrict__ Wk = weight + (long)k * CIN * COUT;
    #pragma unroll
    for (int c = 0; c < CIN; ++c) w[c] = Wk[c * COUT + lane];

    const int base    = k * P;
    const int nchunks = (P + 31) >> 5;

    for (int ch = group_id; ch < nchunks; ch += n_groups) {
        const int p0 = ch << 5;
        const int n  = min(32, P - p0);

        // Coalesced index loads: lane j holds pair p0+j's indices.
        int my_in = 0, my_out = 0;
        if (lane < n) {
            my_in  = in_idx[base + p0 + lane];
            my_out = out_idx[base + p0 + lane];
        }

        #pragma unroll 4
        for (int j = 0; j < n; ++j) {
            const int in = __shfl(my_in,  j, 32);
            const int o  = __shfl(my_out, j, 32);
            const float4* __restrict__ fr =
                reinterpret_cast<const float4*>(feats + (long)in * CIN);
            float acc = 0.0f;
            #pragma unroll
            for (int c4 = 0; c4 < CIN / 4; ++c4) {
                float4 f = fr[c4];         // group-uniform broadcast load
                acc += f.x * w[4 * c4 + 0];
                acc += f.y * w[4 * c4 + 1];
                acc += f.z * w[4 * c4 + 2];
                acc += f.w * w[4 * c4 + 3];
            }
            atomicAdd(out + (long)o * COUT + lane, acc);
        }
    }
}

extern "C" void kernel_launch(void* const* d_in, const int* in_sizes, int n_in,
                              void* d_out, int out_size, void* d_ws, size_t ws_size,
                              hipStream_t stream) {
    const float* feats   = (const float*)d_in[0];
    const float* weight  = (const float*)d_in[1];
    const float* bias    = (const float*)d_in[2];
    const int*   in_idx  = (const int*)d_in[3];
    const int*   out_idx = (const int*)d_in[4];
    float*       out     = (float*)d_out;

    const int K = in_sizes[1] / (CIN * COUT);   // 27
    const int P = in_sizes[3] / K;              // 50000

    // 1) out = bias (broadcast)
    int total4 = out_size / 4;
    bias_init_kernel<<<(total4 + 255) / 256, 256, 0, stream>>>(out, bias, out_size);

    // 2) gather -> GEMV -> scatter-add
    const int blocks_x = 96;                    // 96*8 = 768 groups per k
    const int n_groups = blocks_x * (256 / 32);
    dim3 grid(blocks_x, K);
    scatter_gemm_kernel<<<grid, 256, 0, stream>>>(feats, weight, in_idx, out_idx,
                                                  out, P, n_groups);
}